// Round 18
// baseline (130.445 us; speedup 1.0000x reference)
//
#include <hip/hip_runtime.h>
#include <hip/hip_bf16.h>
#include <math.h>

#define B_ 4
#define S_ 2048
#define D_ 512
#define E_ 512
#define H_ 8
#define HD_ 64
#define ALPHA_ 1.0f
#define M_ (B_*S_)   // 8192
#define LOG2E_ 1.44269504088896340736f

typedef __attribute__((ext_vector_type(8))) short bf16x8;
typedef __attribute__((ext_vector_type(4))) float f32x4;

__device__ inline unsigned short f2bf(float f) {
    union { __hip_bfloat16 h; unsigned short u; } cv;
    cv.h = __float2bfloat16(f);
    return cv.u;
}
__device__ inline unsigned pack2bf(float a, float b) {
    union { __hip_bfloat162 h; unsigned u; } cv;
    cv.h = __float22bfloat162_rn(make_float2(a, b));
    return cv.u;
}
// async global -> LDS. Global src is PER-LANE; LDS dst is wave-uniform base,
// HW writes lane i at base + i*size (m104/m173).
__device__ inline void gload16(const void* g, void* l) {
    __builtin_amdgcn_global_load_lds(
        (const __attribute__((address_space(1))) unsigned int*)g,
        (__attribute__((address_space(3))) unsigned int*)l, 16, 0, 0);
}
__device__ inline void gload4(const void* g, void* l) {
    __builtin_amdgcn_global_load_lds(
        (const __attribute__((address_space(1))) unsigned int*)g,
        (__attribute__((address_space(3))) unsigned int*)l, 4, 0, 0);
}

// ---------------------------------------------------------------------------
// prep: blocks 0..2047: x -> bf16 + per-block max ||x_row||^2 (no atomics)
//       blocks 2048..2559: Wqkv,Wo -> bf16.  Block 0 also zeroes the
//       QKV-GEMM completion counter (graph-replay-safe re-init).
// ---------------------------------------------------------------------------
__global__ __launch_bounds__(256) void prep(const float* __restrict__ x,
                                            const float* __restrict__ Wqkv,
                                            const float* __restrict__ Wo,
                                            unsigned short* __restrict__ xbf,
                                            unsigned short* __restrict__ Wqkvb,
                                            unsigned short* __restrict__ Wob,
                                            float* __restrict__ xmax,
                                            unsigned int* __restrict__ cnt) {
    const int t   = threadIdx.x;
    const int bid = blockIdx.x;
    if (bid == 0 && t == 0) *cnt = 0u;
    if (bid < 2048) {
        __shared__ float red[4];
        const int wid = t >> 6, lane = t & 63;
        const int row = bid * 4 + wid;
        const float* xr = &x[(size_t)row * D_ + lane * 8];
        const float4 a = *(const float4*)xr;
        const float4 b = *(const float4*)(xr + 4);
        float ss = a.x*a.x + a.y*a.y + a.z*a.z + a.w*a.w
                 + b.x*b.x + b.y*b.y + b.z*b.z + b.w*b.w;
        uint4 o;
        o.x = pack2bf(a.x, a.y); o.y = pack2bf(a.z, a.w);
        o.z = pack2bf(b.x, b.y); o.w = pack2bf(b.z, b.w);
        *(uint4*)&xbf[(size_t)row * D_ + lane * 8] = o;
        #pragma unroll
        for (int off = 32; off; off >>= 1) ss += __shfl_xor(ss, off);
        if (lane == 0) red[wid] = ss;
        __syncthreads();
        if (t == 0)
            xmax[bid] = fmaxf(fmaxf(red[0], red[1]), fmaxf(red[2], red[3]));
    } else {
        const int i  = (bid - 2048) * 256 + t;       // 0..131071
        const int nq = 3 * E_ * D_ / 8;              // 98304
        const float* src; unsigned short* dst; int j;
        if (i < nq) { src = Wqkv; dst = Wqkvb; j = i; }
        else        { src = Wo;   dst = Wob;   j = i - nq; }
        const float4 a = *(const float4*)&src[(size_t)j * 8];
        const float4 b = *(const float4*)&src[(size_t)j * 8 + 4];
        uint4 o;
        o.x = pack2bf(a.x, a.y); o.y = pack2bf(a.z, a.w);
        o.z = pack2bf(b.x, b.y); o.w = pack2bf(b.z, b.w);
        *(uint4*)&dst[(size_t)j * 8] = o;
    }
}

// ---------------------------------------------------------------------------
// bf16 MFMA GEMM (R15 structure): 128x128 tile, BK=64, dbuf gload_lds,
// setprio around MFMA. MODE 0 additionally: the LAST block to finish
// (atomic counter) reduces sum(q^2) partials + xmax -> SCAL (deterministic:
// one block, fixed order). No extra dispatch, no spin.
// ---------------------------------------------------------------------------
template<int N, int MODE>
__global__ __launch_bounds__(256) void gemm_mfma(const unsigned short* __restrict__ Abf,
                                                 const unsigned short* __restrict__ Wbf,
                                                 const float* __restrict__ bias,
                                                 void* __restrict__ out0,
                                                 void* __restrict__ out1,
                                                 void* __restrict__ out2,
                                                 float* __restrict__ part,
                                                 float* __restrict__ kn2,
                                                 const float* __restrict__ xmax,
                                                 float* __restrict__ scal,
                                                 unsigned int* __restrict__ cnt) {
    __shared__ __align__(16) char At[2][16384];
    __shared__ __align__(16) char Wt[2][16384];

    const int t  = threadIdx.x;
    const int w  = t >> 6;
    const int l  = t & 63;
    const int g  = l >> 4;
    const int c  = l & 15;
    const int wm = w >> 1;
    const int wn = w & 1;
    const int m0 = blockIdx.y * 128;
    const int n0 = blockIdx.x * 128;

    f32x4 acc[4][4];
    #pragma unroll
    for (int i = 0; i < 4; ++i)
        #pragma unroll
        for (int j = 0; j < 4; ++j)
            #pragma unroll
            for (int r = 0; r < 4; ++r) acc[i][j][r] = 0.f;

    const int lr3 = l >> 3;
    const int colSwz = ((l & 7) * 16) ^ (lr3 << 4);
    const char* pA = (const char*)Abf + (size_t)(m0 + w * 8 + lr3) * 1024 + colSwz;
    const char* pB = (const char*)Wbf + (size_t)(n0 + w * 8 + lr3) * 1024 + colSwz;

    auto gstage = [&](int k0, int buf) {
        #pragma unroll
        for (int j = 0; j < 4; ++j) {
            gload16(pA + (size_t)j * 32768 + (size_t)k0 * 2, At[buf] + w * 1024 + j * 4096);
            gload16(pB + (size_t)j * 32768 + (size_t)k0 * 2, Wt[buf] + w * 1024 + j * 4096);
        }
    };

    gstage(0, 0);
    __syncthreads();
    for (int i = 0; i < 8; ++i) {
        const int buf = i & 1;
        if (i < 7) gstage((i + 1) * 64, buf ^ 1);

        bf16x8 af[4][2], wf[4][2];
        #pragma unroll
        for (int mt = 0; mt < 4; ++mt) {
            const int row = wm * 64 + mt * 16 + c;
            const int sw  = (row & 7) << 4;
            #pragma unroll
            for (int kc = 0; kc < 2; ++kc)
                af[mt][kc] = *(const bf16x8*)(At[buf] + row * 128 + (((kc * 4 + g) * 16) ^ sw));
        }
        #pragma unroll
        for (int nt = 0; nt < 4; ++nt) {
            const int row = wn * 64 + nt * 16 + c;
            const int sw  = (row & 7) << 4;
            #pragma unroll
            for (int kc = 0; kc < 2; ++kc)
                wf[nt][kc] = *(const bf16x8*)(Wt[buf] + row * 128 + (((kc * 4 + g) * 16) ^ sw));
        }
        __builtin_amdgcn_s_setprio(1);
        #pragma unroll
        for (int mt = 0; mt < 4; ++mt)
            #pragma unroll
            for (int nt = 0; nt < 4; ++nt) {
                acc[mt][nt] = __builtin_amdgcn_mfma_f32_16x16x32_bf16(af[mt][0], wf[nt][0], acc[mt][nt], 0, 0, 0);
                acc[mt][nt] = __builtin_amdgcn_mfma_f32_16x16x32_bf16(af[mt][1], wf[nt][1], acc[mt][nt], 0, 0, 0);
            }
        __builtin_amdgcn_s_setprio(0);
        __syncthreads();
    }

    if (MODE == 1) {
        #pragma unroll
        for (int mt = 0; mt < 4; ++mt)
            #pragma unroll
            for (int reg = 0; reg < 4; ++reg) {
                const int m = m0 + wm * 64 + mt * 16 + g * 4 + reg;
                #pragma unroll
                for (int nt = 0; nt < 4; ++nt) {
                    const int n = n0 + wn * 64 + nt * 16 + c;
                    ((float*)out0)[(size_t)m * N + n] = acc[mt][nt][reg] + bias[n];
                }
            }
        return;
    }

    const int hb  = 2 * blockIdx.x + wn;
    const int cls = hb % 3;
    const int h   = hb / 3;
    const int b   = m0 >> 11;
    const int s0w = (m0 & 2047) + wm * 64;
    const size_t bhS = ((size_t)b * H_ + h) * S_;

    float kp[4][4];
    #pragma unroll
    for (int i = 0; i < 4; ++i)
        #pragma unroll
        for (int j = 0; j < 4; ++j) kp[i][j] = 0.f;

    if (cls == 2) {
        unsigned short* Vt_ = (unsigned short*)out2;
        #pragma unroll
        for (int nt = 0; nt < 4; ++nt) {
            const int n = n0 + wn * 64 + nt * 16 + c;
            const float bv = bias[n];
            const int d = nt * 16 + c;
            unsigned short* dbase = Vt_ + (((size_t)b * H_ + h) * HD_ + d) * S_ + s0w;
            #pragma unroll
            for (int mt = 0; mt < 4; ++mt) {
                uint2 pk;
                pk.x = pack2bf(acc[mt][nt][0] + bv, acc[mt][nt][1] + bv);
                pk.y = pack2bf(acc[mt][nt][2] + bv, acc[mt][nt][3] + bv);
                *(uint2*)&dbase[mt * 16 + g * 4] = pk;
            }
        }
    } else {
        unsigned short* dst0 = (cls == 0) ? (unsigned short*)out0 : (unsigned short*)out1;
        #pragma unroll
        for (int nt = 0; nt < 4; ++nt) {
            const int n = n0 + wn * 64 + nt * 16 + c;
            const float bv = bias[n];
            const int d = nt * 16 + c;
            #pragma unroll
            for (int mt = 0; mt < 4; ++mt)
                #pragma unroll
                for (int reg = 0; reg < 4; ++reg) {
                    const int s = s0w + mt * 16 + g * 4 + reg;
                    const float val = acc[mt][nt][reg] + bv;
                    kp[mt][reg] = fmaf(val, val, kp[mt][reg]);
                    dst0[(bhS + s) * HD_ + d] = f2bf(val);
                }
        }
    }

    __syncthreads();
    if (cls == 1) {
        float* scratch = (float*)&At[0][0] + wm * 1088;
        #pragma unroll
        for (int i = 0; i < 16; ++i) scratch[l * 17 + i] = kp[i >> 2][i & 3];
        asm volatile("s_waitcnt lgkmcnt(0)" ::: "memory");
        __builtin_amdgcn_sched_barrier(0);
        float sum = 0.f;
        #pragma unroll
        for (int cc = 0; cc < 16; ++cc)
            sum += scratch[(g * 16 + cc) * 17 + c];
        const int s = s0w + (c >> 2) * 16 + g * 4 + (c & 3);
        kn2[bhS + s] = sum;
    }
    __syncthreads();

    float qss = 0.f;
    if (cls == 0) {
        #pragma unroll
        for (int i = 0; i < 4; ++i)
            #pragma unroll
            for (int j = 0; j < 4; ++j) qss += kp[i][j];
    }
    float* red = (float*)&At[0][0];
    red[t] = qss;
    __syncthreads();
    for (int s = 128; s; s >>= 1) {
        if (t < s) red[t] += red[t + s];
        __syncthreads();
    }
    __shared__ unsigned int done;
    if (t == 0) {
        part[blockIdx.y * gridDim.x + blockIdx.x] = red[0];
        __threadfence();
        done = atomicAdd(cnt, 1u);
    }
    __syncthreads();
    if (done == 767u) {
        // last block: reduce partials + xmax -> SCAL (fixed order, determ.)
        __threadfence();
        float* rs = (float*)&At[0][0];
        float* rm = rs + 256;
        float ss = 0.f, mx = 0.f;
        for (int i = t; i < 768; i += 256) ss += part[i];
        for (int i = t; i < 2048; i += 256) mx = fmaxf(mx, xmax[i]);
        rs[t] = ss; rm[t] = mx;
        __syncthreads();
        for (int s = 128; s; s >>= 1) {
            if (t < s) { rs[t] += rs[t + s]; rm[t] = fmaxf(rm[t], rm[t + s]); }
            __syncthreads();
        }
        if (t == 0)
            scal[0] = ALPHA_ * LOG2E_ / (sqrtf(rs[0]) * sqrtf(rm[0]));
    }
}

// ---------------------------------------------------------------------------
// bf16 MFMA flash attention (R13 core verbatim; SCAL precomputed; native
// exp2). 512 thr = 8 waves, 128 q/block, KV tile 64. gload_lds dbuf,
// 1 barrier/tile, exp2 domain, fixed m=0, per-lane partial l.
// LDS: K 2x8K | V 2x8K | P 8x2K | kn 2x256B = 48.5 KB.
// ---------------------------------------------------------------------------
__global__ __launch_bounds__(512, 2) void attn_mfma(const unsigned short* __restrict__ Qb,
                                                    const unsigned short* __restrict__ Kb,
                                                    const unsigned short* __restrict__ Vtb,
                                                    const float* __restrict__ KN2,
                                                    const float* __restrict__ SCAL,
                                                    unsigned short* __restrict__ VALS) {
    __shared__ __align__(16) char lds[49664];
    char* Kl = lds;                  // 2 x [64 k][64 d] bf16, swizzled content
    char* Vl = lds + 16384;          // 2 x [64 d][64 k] bf16, swizzled content
    char* Pl = lds + 32768;          // 8 waves x [16 q][64 k] bf16, swizzled
    char* knl = lds + 49152;         // 2 x 64 floats

    const int t  = threadIdx.x;
    const int w  = t >> 6;           // 0..7
    const int l  = t & 63;
    const int g  = l >> 4;
    const int c  = l & 15;
    // XCD swizzle: 512 blocks, 8 XCDs -> 64 contiguous (4 bh) per XCD
    const int bid  = blockIdx.y * gridDim.x + blockIdx.x;
    const int swid = (bid & 7) * 64 + (bid >> 3);
    const int bh = swid >> 4;        // 0..31
    const int qb = swid & 15;        // 0..15

    const float sc    = SCAL[0];
    const float ts2   = 2.0f * sc;
    const float nscal = -sc;

    const int qrow = qb * 128 + w * 16 + c;
    const size_t qoff = ((size_t)bh * S_ + qrow) * HD_;
    const bf16x8 qf0 = *(const bf16x8*)&Qb[qoff + g * 8];
    const bf16x8 qf1 = *(const bf16x8*)&Qb[qoff + 32 + g * 8];

    f32x4 acc[4];
    #pragma unroll
    for (int dt = 0; dt < 4; ++dt)
        #pragma unroll
        for (int r = 0; r < 4; ++r) acc[dt][r] = 0.f;
    float lpart = 0.f;

    const float* kn2g = &KN2[(size_t)bh * S_];
    char* Pw = Pl + w * 2048;
    const int swc = (c & 7) << 4;

    int offF[4][2];
    #pragma unroll
    for (int i = 0; i < 4; ++i) {
        offF[i][0] = (i * 16 + c) * 128 + ((g * 16) ^ swc);
        offF[i][1] = (i * 16 + c) * 128 + ((64 + g * 16) ^ swc);
    }
    int offPW[4];
    #pragma unroll
    for (int kt = 0; kt < 4; ++kt)
        offPW[kt] = c * 128 + ((kt * 32 + g * 8) ^ swc);
    const int offPA0 = c * 128 + ((g * 16) ^ swc);
    const int offPA1 = c * 128 + ((64 + g * 16) ^ swc);

    const int lr3 = l >> 3;
    const int colSwz = ((l & 7) * 16) ^ (lr3 << 4);
    const char* pK = (const char*)Kb + ((size_t)bh * S_ * HD_) * 2
                   + (size_t)(w * 8 + lr3) * 128 + colSwz;
    const char* pV = (const char*)Vtb + ((size_t)bh * HD_ * S_) * 2
                   + (size_t)(w * 8 + lr3) * (S_ * 2) + colSwz;
    char* lK = Kl + w * 1024;
    char* lV = Vl + w * 1024;

#define STAGE(T, buf) do {                                                    \
        gload16(pK + (size_t)(T) * 8192, lK + (buf) * 8192);                  \
        gload16(pV + (size_t)(T) * 128,  lV + (buf) * 8192);                  \
        if (w == 0) gload4(kn2g + (T) * 64 + l, knl + (buf) * 256);           \
    } while (0)

    auto compute_tile = [&](int cur) {
        const char* Kc = Kl + cur * 8192;
        const char* Vc = Vl + cur * 8192;
        const float* knc = (const float*)(knl + cur * 256);
        float sl[16];
        #pragma unroll
        for (int kt = 0; kt < 4; ++kt) {
            const bf16x8 ka0 = *(const bf16x8*)(Kc + offF[kt][0]);
            const bf16x8 ka1 = *(const bf16x8*)(Kc + offF[kt][1]);
            f32x4 sacc = {0.f, 0.f, 0.f, 0.f};
            sacc = __builtin_amdgcn_mfma_f32_16x16x32_bf16(ka0, qf0, sacc, 0, 0, 0);
            sacc = __builtin_amdgcn_mfma_f32_16x16x32_bf16(ka1, qf1, sacc, 0, 0, 0);
            const f32x4 kn4 = *(const f32x4*)&knc[kt * 16 + g * 4];
            #pragma unroll
            for (int rg = 0; rg < 4; ++rg)
                sl[kt * 4 + rg] = fmaf(sacc[rg], ts2, nscal * kn4[rg]);
        }

        float p[16];
        #pragma unroll
        for (int j = 0; j < 16; ++j) {
            p[j] = __builtin_amdgcn_exp2f(sl[j]);   // native v_exp_f32
            lpart += p[j];
        }

        #pragma unroll
        for (int kt = 0; kt < 4; ++kt) {
            uint2 pk;
            pk.x = pack2bf(p[kt * 4 + 0], p[kt * 4 + 1]);
            pk.y = pack2bf(p[kt * 4 + 2], p[kt * 4 + 3]);
            *(uint2*)(Pw + offPW[kt]) = pk;
        }
        asm volatile("s_waitcnt lgkmcnt(0)" ::: "memory");
        __builtin_amdgcn_sched_barrier(0);

        const bf16x8 pa0 = *(const bf16x8*)(Pw + offPA0);
        const bf16x8 pa1 = *(const bf16x8*)(Pw + offPA1);
        #pragma unroll
        for (int dt = 0; dt < 4; ++dt) {
            const bf16x8 vb0 = *(const bf16x8*)(Vc + offF[dt][0]);
            const bf16x8 vb1 = *(const bf16x8*)(Vc + offF[dt][1]);
            acc[dt] = __builtin_amdgcn_mfma_f32_16x16x32_bf16(pa0, vb0, acc[dt], 0, 0, 0);
            acc[dt] = __builtin_amdgcn_mfma_f32_16x16x32_bf16(pa1, vb1, acc[dt], 0, 0, 0);
        }
    };

    STAGE(0, 0);
    __syncthreads();                 // drain prologue stage
    for (int T = 0; T < 32; ++T) {
        const int cur = T & 1;
        if (T < 31) STAGE(T + 1, cur ^ 1);   // overlaps with compute below
        compute_tile(cur);
        __syncthreads();             // readers done + next stage drained
    }
#undef STAGE

    lpart += __shfl_xor(lpart, 16);
    lpart += __shfl_xor(lpart, 32);

    const int b = bh >> 3, h = bh & 7;
    #pragma unroll
    for (int reg = 0; reg < 4; ++reg) {
        const float lq  = __shfl(lpart, g * 4 + reg);
        const float inv = 1.0f / lq;
        const int qg = qb * 128 + w * 16 + g * 4 + reg;
        unsigned short* dst = &VALS[((size_t)b * S_ + qg) * E_ + h * HD_];
        #pragma unroll
        for (int dt = 0; dt < 4; ++dt)
            dst[dt * 16 + c] = f2bf(acc[dt][reg] * inv);
    }
}

// ---------------------------------------------------------------------------
extern "C" void kernel_launch(void* const* d_in, const int* in_sizes, int n_in,
                              void* d_out, int out_size, void* d_ws, size_t ws_size,
                              hipStream_t stream) {
    const float* x    = (const float*)d_in[0];
    const float* Wqkv = (const float*)d_in[1];
    const float* bqkv = (const float*)d_in[2];
    const float* Wo   = (const float*)d_in[3];
    const float* bo   = (const float*)d_in[4];
    float* out = (float*)d_out;

    char* ws = (char*)d_ws;
    unsigned short* Qb    = (unsigned short*)(ws);                        // 8 MB
    unsigned short* Kb    = (unsigned short*)(ws + ((size_t) 8 << 20));   // 8 MB
    unsigned short* Vtb   = (unsigned short*)(ws + ((size_t)16 << 20));   // 8 MB
    unsigned short* VALb  = (unsigned short*)(ws + ((size_t)24 << 20));   // 8 MB
    unsigned short* xbf   = (unsigned short*)(ws + ((size_t)32 << 20));   // 8 MB
    unsigned short* Wqkvb = (unsigned short*)(ws + ((size_t)40 << 20));   // 1.5 MB
    unsigned short* Wob   = (unsigned short*)(ws + ((size_t)42 << 20));   // 0.5 MB
    float* KN2  = (float*)(ws + ((size_t)43 << 20));                      // 256 KB
    float* PART = (float*)(ws + ((size_t)43 << 20) + (256 << 10));        // 3 KB
    float* XMAX = (float*)(ws + ((size_t)43 << 20) + (260 << 10));        // 8 KB
    float* SCAL = (float*)(ws + ((size_t)43 << 20) + (272 << 10));
    unsigned int* CNT = (unsigned int*)(SCAL + 4);

    // 0) x -> bf16 + per-block row-norm max; weights -> bf16; counter reset
    prep<<<2560, 256, 0, stream>>>(x, Wqkv, Wo, xbf, Wqkvb, Wob, XMAX, CNT);

    // 1) QKV projection + q^2/k^2 stats + last-block SCAL reduction
    gemm_mfma<3 * E_, 0><<<dim3(12, 64), 256, 0, stream>>>(
        xbf, Wqkvb, bqkv, Qb, Kb, Vtb, PART, KN2, XMAX, SCAL, CNT);

    // 2) MFMA flash attention (R13 core, native exp2) -> VAL bf16 [B,S,E]
    attn_mfma<<<dim3(16, 32), 512, 0, stream>>>(Qb, Kb, Vtb, KN2, SCAL, VALb);

    // 3) output projection (bf16 MFMA, dbuf, fp32 out)
    gemm_mfma<E_, 1><<<dim3(4, 64), 256, 0, stream>>>(
        VALb, Wob, bo, out, nullptr, nullptr, nullptr, nullptr, nullptr, nullptr, nullptr);
}

// Round 19
// 101.676 us; speedup vs baseline: 1.2829x; 1.2829x over previous
//
#include <hip/hip_runtime.h>
#include <hip/hip_bf16.h>
#include <math.h>

#define B_ 4
#define S_ 2048
#define D_ 512
#define E_ 512
#define H_ 8
#define HD_ 64
#define ALPHA_ 1.0f
#define M_ (B_*S_)   // 8192
#define LOG2E_ 1.44269504088896340736f

typedef __attribute__((ext_vector_type(8))) short bf16x8;
typedef __attribute__((ext_vector_type(4))) float f32x4;

__device__ inline unsigned short f2bf(float f) {
    union { __hip_bfloat16 h; unsigned short u; } cv;
    cv.h = __float2bfloat16(f);
    return cv.u;
}
__device__ inline unsigned pack2bf(float a, float b) {
    union { __hip_bfloat162 h; unsigned u; } cv;
    cv.h = __float22bfloat162_rn(make_float2(a, b));
    return cv.u;
}
// async global -> LDS. Global src is PER-LANE; LDS dst is wave-uniform base,
// HW writes lane i at base + i*size (m104/m173).
__device__ inline void gload16(const void* g, void* l) {
    __builtin_amdgcn_global_load_lds(
        (const __attribute__((address_space(1))) unsigned int*)g,
        (__attribute__((address_space(3))) unsigned int*)l, 16, 0, 0);
}
__device__ inline void gload4(const void* g, void* l) {
    __builtin_amdgcn_global_load_lds(
        (const __attribute__((address_space(1))) unsigned int*)g,
        (__attribute__((address_space(3))) unsigned int*)l, 4, 0, 0);
}

// ---------------------------------------------------------------------------
// prep: blocks 0..2047: x -> bf16 + per-block max ||x_row||^2 (no atomics)
//       blocks 2048..2559: Wqkv,Wo -> bf16
// ---------------------------------------------------------------------------
__global__ __launch_bounds__(256) void prep(const float* __restrict__ x,
                                            const float* __restrict__ Wqkv,
                                            const float* __restrict__ Wo,
                                            unsigned short* __restrict__ xbf,
                                            unsigned short* __restrict__ Wqkvb,
                                            unsigned short* __restrict__ Wob,
                                            float* __restrict__ xmax) {
    const int t   = threadIdx.x;
    const int bid = blockIdx.x;
    if (bid < 2048) {
        __shared__ float red[4];
        const int wid = t >> 6, lane = t & 63;
        const int row = bid * 4 + wid;
        const float* xr = &x[(size_t)row * D_ + lane * 8];
        const float4 a = *(const float4*)xr;
        const float4 b = *(const float4*)(xr + 4);
        float ss = a.x*a.x + a.y*a.y + a.z*a.z + a.w*a.w
                 + b.x*b.x + b.y*b.y + b.z*b.z + b.w*b.w;
        uint4 o;
        o.x = pack2bf(a.x, a.y); o.y = pack2bf(a.z, a.w);
        o.z = pack2bf(b.x, b.y); o.w = pack2bf(b.z, b.w);
        *(uint4*)&xbf[(size_t)row * D_ + lane * 8] = o;
        #pragma unroll
        for (int off = 32; off; off >>= 1) ss += __shfl_xor(ss, off);
        if (lane == 0) red[wid] = ss;
        __syncthreads();
        if (t == 0)
            xmax[bid] = fmaxf(fmaxf(red[0], red[1]), fmaxf(red[2], red[3]));
    } else {
        const int i  = (bid - 2048) * 256 + t;       // 0..131071
        const int nq = 3 * E_ * D_ / 8;              // 98304
        const float* src; unsigned short* dst; int j;
        if (i < nq) { src = Wqkv; dst = Wqkvb; j = i; }
        else        { src = Wo;   dst = Wob;   j = i - nq; }
        const float4 a = *(const float4*)&src[(size_t)j * 8];
        const float4 b = *(const float4*)&src[(size_t)j * 8 + 4];
        uint4 o;
        o.x = pack2bf(a.x, a.y); o.y = pack2bf(a.z, a.w);
        o.z = pack2bf(b.x, b.y); o.w = pack2bf(b.z, b.w);
        *(uint4*)&dst[(size_t)j * 8] = o;
    }
}

// ---------------------------------------------------------------------------
// bf16 MFMA GEMM (R15 structure, NO scal machinery): 128x128 tile, BK=64,
// dbuf gload_lds, setprio around MFMA.
// MODE 0: q/k/v scatter + sum(q^2) partials + per-key ||k||^2.
// MODE 1: fp32 C row-major [M][N]
// ---------------------------------------------------------------------------
template<int N, int MODE>
__global__ __launch_bounds__(256) void gemm_mfma(const unsigned short* __restrict__ Abf,
                                                 const unsigned short* __restrict__ Wbf,
                                                 const float* __restrict__ bias,
                                                 void* __restrict__ out0,
                                                 void* __restrict__ out1,
                                                 void* __restrict__ out2,
                                                 float* __restrict__ part,
                                                 float* __restrict__ kn2) {
    __shared__ __align__(16) char At[2][16384];
    __shared__ __align__(16) char Wt[2][16384];

    const int t  = threadIdx.x;
    const int w  = t >> 6;
    const int l  = t & 63;
    const int g  = l >> 4;
    const int c  = l & 15;
    const int wm = w >> 1;
    const int wn = w & 1;
    const int m0 = blockIdx.y * 128;
    const int n0 = blockIdx.x * 128;

    f32x4 acc[4][4];
    #pragma unroll
    for (int i = 0; i < 4; ++i)
        #pragma unroll
        for (int j = 0; j < 4; ++j)
            #pragma unroll
            for (int r = 0; r < 4; ++r) acc[i][j][r] = 0.f;

    const int lr3 = l >> 3;
    const int colSwz = ((l & 7) * 16) ^ (lr3 << 4);
    const char* pA = (const char*)Abf + (size_t)(m0 + w * 8 + lr3) * 1024 + colSwz;
    const char* pB = (const char*)Wbf + (size_t)(n0 + w * 8 + lr3) * 1024 + colSwz;

    auto gstage = [&](int k0, int buf) {
        #pragma unroll
        for (int j = 0; j < 4; ++j) {
            gload16(pA + (size_t)j * 32768 + (size_t)k0 * 2, At[buf] + w * 1024 + j * 4096);
            gload16(pB + (size_t)j * 32768 + (size_t)k0 * 2, Wt[buf] + w * 1024 + j * 4096);
        }
    };

    gstage(0, 0);
    __syncthreads();
    for (int i = 0; i < 8; ++i) {
        const int buf = i & 1;
        if (i < 7) gstage((i + 1) * 64, buf ^ 1);

        bf16x8 af[4][2], wf[4][2];
        #pragma unroll
        for (int mt = 0; mt < 4; ++mt) {
            const int row = wm * 64 + mt * 16 + c;
            const int sw  = (row & 7) << 4;
            #pragma unroll
            for (int kc = 0; kc < 2; ++kc)
                af[mt][kc] = *(const bf16x8*)(At[buf] + row * 128 + (((kc * 4 + g) * 16) ^ sw));
        }
        #pragma unroll
        for (int nt = 0; nt < 4; ++nt) {
            const int row = wn * 64 + nt * 16 + c;
            const int sw  = (row & 7) << 4;
            #pragma unroll
            for (int kc = 0; kc < 2; ++kc)
                wf[nt][kc] = *(const bf16x8*)(Wt[buf] + row * 128 + (((kc * 4 + g) * 16) ^ sw));
        }
        __builtin_amdgcn_s_setprio(1);
        #pragma unroll
        for (int mt = 0; mt < 4; ++mt)
            #pragma unroll
            for (int nt = 0; nt < 4; ++nt) {
                acc[mt][nt] = __builtin_amdgcn_mfma_f32_16x16x32_bf16(af[mt][0], wf[nt][0], acc[mt][nt], 0, 0, 0);
                acc[mt][nt] = __builtin_amdgcn_mfma_f32_16x16x32_bf16(af[mt][1], wf[nt][1], acc[mt][nt], 0, 0, 0);
            }
        __builtin_amdgcn_s_setprio(0);
        __syncthreads();
    }

    if (MODE == 1) {
        #pragma unroll
        for (int mt = 0; mt < 4; ++mt)
            #pragma unroll
            for (int reg = 0; reg < 4; ++reg) {
                const int m = m0 + wm * 64 + mt * 16 + g * 4 + reg;
                #pragma unroll
                for (int nt = 0; nt < 4; ++nt) {
                    const int n = n0 + wn * 64 + nt * 16 + c;
                    ((float*)out0)[(size_t)m * N + n] = acc[mt][nt][reg] + bias[n];
                }
            }
        return;
    }

    const int hb  = 2 * blockIdx.x + wn;
    const int cls = hb % 3;
    const int h   = hb / 3;
    const int b   = m0 >> 11;
    const int s0w = (m0 & 2047) + wm * 64;
    const size_t bhS = ((size_t)b * H_ + h) * S_;

    float kp[4][4];
    #pragma unroll
    for (int i = 0; i < 4; ++i)
        #pragma unroll
        for (int j = 0; j < 4; ++j) kp[i][j] = 0.f;

    if (cls == 2) {
        unsigned short* Vt_ = (unsigned short*)out2;
        #pragma unroll
        for (int nt = 0; nt < 4; ++nt) {
            const int n = n0 + wn * 64 + nt * 16 + c;
            const float bv = bias[n];
            const int d = nt * 16 + c;
            unsigned short* dbase = Vt_ + (((size_t)b * H_ + h) * HD_ + d) * S_ + s0w;
            #pragma unroll
            for (int mt = 0; mt < 4; ++mt) {
                uint2 pk;
                pk.x = pack2bf(acc[mt][nt][0] + bv, acc[mt][nt][1] + bv);
                pk.y = pack2bf(acc[mt][nt][2] + bv, acc[mt][nt][3] + bv);
                *(uint2*)&dbase[mt * 16 + g * 4] = pk;
            }
        }
    } else {
        unsigned short* dst0 = (cls == 0) ? (unsigned short*)out0 : (unsigned short*)out1;
        #pragma unroll
        for (int nt = 0; nt < 4; ++nt) {
            const int n = n0 + wn * 64 + nt * 16 + c;
            const float bv = bias[n];
            const int d = nt * 16 + c;
            #pragma unroll
            for (int mt = 0; mt < 4; ++mt)
                #pragma unroll
                for (int reg = 0; reg < 4; ++reg) {
                    const int s = s0w + mt * 16 + g * 4 + reg;
                    const float val = acc[mt][nt][reg] + bv;
                    kp[mt][reg] = fmaf(val, val, kp[mt][reg]);
                    dst0[(bhS + s) * HD_ + d] = f2bf(val);
                }
        }
    }

    __syncthreads();
    if (cls == 1) {
        float* scratch = (float*)&At[0][0] + wm * 1088;
        #pragma unroll
        for (int i = 0; i < 16; ++i) scratch[l * 17 + i] = kp[i >> 2][i & 3];
        asm volatile("s_waitcnt lgkmcnt(0)" ::: "memory");
        __builtin_amdgcn_sched_barrier(0);
        float sum = 0.f;
        #pragma unroll
        for (int cc = 0; cc < 16; ++cc)
            sum += scratch[(g * 16 + cc) * 17 + c];
        const int s = s0w + (c >> 2) * 16 + g * 4 + (c & 3);
        kn2[bhS + s] = sum;
    }
    __syncthreads();

    float qss = 0.f;
    if (cls == 0) {
        #pragma unroll
        for (int i = 0; i < 4; ++i)
            #pragma unroll
            for (int j = 0; j < 4; ++j) qss += kp[i][j];
    }
    float* red = (float*)&At[0][0];
    red[t] = qss;
    __syncthreads();
    for (int s = 128; s; s >>= 1) {
        if (t < s) red[t] += red[t + s];
        __syncthreads();
    }
    if (t == 0) part[blockIdx.y * gridDim.x + blockIdx.x] = red[0];
}

// ---------------------------------------------------------------------------
// finalize: scal = ALPHA*log2(e) / (sqrt(sum q^2) * sqrt(max row norm^2))
// ---------------------------------------------------------------------------
__global__ __launch_bounds__(256) void finalize_scale(const float* __restrict__ part,
                                                      const float* __restrict__ xmax,
                                                      float* __restrict__ scal) {
    __shared__ float rs[256], rm[256];
    const int t = threadIdx.x;
    float ss = 0.f, mx = 0.f;
    for (int i = t; i < 768; i += 256) ss += part[i];
    for (int i = t; i < 2048; i += 256) mx = fmaxf(mx, xmax[i]);
    rs[t] = ss; rm[t] = mx;
    __syncthreads();
    for (int s = 128; s; s >>= 1) {
        if (t < s) { rs[t] += rs[t + s]; rm[t] = fmaxf(rm[t], rm[t + s]); }
        __syncthreads();
    }
    if (t == 0) scal[0] = ALPHA_ * LOG2E_ / (sqrtf(rs[0]) * sqrtf(rm[0]));
}

// ---------------------------------------------------------------------------
// bf16 MFMA flash attention (R13 core; SCAL precomputed; native exp2).
// 512 thr = 8 waves, 128 q/block, KV tile 64. gload_lds dbuf, 1 barrier/
// tile, exp2 domain, fixed m=0, per-lane partial l.
// LDS: K 2x8K | V 2x8K | P 8x2K | kn 2x256B = 48.5 KB.
// ---------------------------------------------------------------------------
__global__ __launch_bounds__(512, 2) void attn_mfma(const unsigned short* __restrict__ Qb,
                                                    const unsigned short* __restrict__ Kb,
                                                    const unsigned short* __restrict__ Vtb,
                                                    const float* __restrict__ KN2,
                                                    const float* __restrict__ SCAL,
                                                    unsigned short* __restrict__ VALS) {
    __shared__ __align__(16) char lds[49664];
    char* Kl = lds;                  // 2 x [64 k][64 d] bf16, swizzled content
    char* Vl = lds + 16384;          // 2 x [64 d][64 k] bf16, swizzled content
    char* Pl = lds + 32768;          // 8 waves x [16 q][64 k] bf16, swizzled
    char* knl = lds + 49152;         // 2 x 64 floats

    const int t  = threadIdx.x;
    const int w  = t >> 6;           // 0..7
    const int l  = t & 63;
    const int g  = l >> 4;
    const int c  = l & 15;
    // XCD swizzle: 512 blocks, 8 XCDs -> 64 contiguous (4 bh) per XCD
    const int bid  = blockIdx.y * gridDim.x + blockIdx.x;
    const int swid = (bid & 7) * 64 + (bid >> 3);
    const int bh = swid >> 4;        // 0..31
    const int qb = swid & 15;        // 0..15

    const float sc    = SCAL[0];
    const float ts2   = 2.0f * sc;
    const float nscal = -sc;

    const int qrow = qb * 128 + w * 16 + c;
    const size_t qoff = ((size_t)bh * S_ + qrow) * HD_;
    const bf16x8 qf0 = *(const bf16x8*)&Qb[qoff + g * 8];
    const bf16x8 qf1 = *(const bf16x8*)&Qb[qoff + 32 + g * 8];

    f32x4 acc[4];
    #pragma unroll
    for (int dt = 0; dt < 4; ++dt)
        #pragma unroll
        for (int r = 0; r < 4; ++r) acc[dt][r] = 0.f;
    float lpart = 0.f;

    const float* kn2g = &KN2[(size_t)bh * S_];
    char* Pw = Pl + w * 2048;
    const int swc = (c & 7) << 4;

    int offF[4][2];
    #pragma unroll
    for (int i = 0; i < 4; ++i) {
        offF[i][0] = (i * 16 + c) * 128 + ((g * 16) ^ swc);
        offF[i][1] = (i * 16 + c) * 128 + ((64 + g * 16) ^ swc);
    }
    int offPW[4];
    #pragma unroll
    for (int kt = 0; kt < 4; ++kt)
        offPW[kt] = c * 128 + ((kt * 32 + g * 8) ^ swc);
    const int offPA0 = c * 128 + ((g * 16) ^ swc);
    const int offPA1 = c * 128 + ((64 + g * 16) ^ swc);

    const int lr3 = l >> 3;
    const int colSwz = ((l & 7) * 16) ^ (lr3 << 4);
    const char* pK = (const char*)Kb + ((size_t)bh * S_ * HD_) * 2
                   + (size_t)(w * 8 + lr3) * 128 + colSwz;
    const char* pV = (const char*)Vtb + ((size_t)bh * HD_ * S_) * 2
                   + (size_t)(w * 8 + lr3) * (S_ * 2) + colSwz;
    char* lK = Kl + w * 1024;
    char* lV = Vl + w * 1024;

#define STAGE(T, buf) do {                                                    \
        gload16(pK + (size_t)(T) * 8192, lK + (buf) * 8192);                  \
        gload16(pV + (size_t)(T) * 128,  lV + (buf) * 8192);                  \
        if (w == 0) gload4(kn2g + (T) * 64 + l, knl + (buf) * 256);           \
    } while (0)

    auto compute_tile = [&](int cur) {
        const char* Kc = Kl + cur * 8192;
        const char* Vc = Vl + cur * 8192;
        const float* knc = (const float*)(knl + cur * 256);
        float sl[16];
        #pragma unroll
        for (int kt = 0; kt < 4; ++kt) {
            const bf16x8 ka0 = *(const bf16x8*)(Kc + offF[kt][0]);
            const bf16x8 ka1 = *(const bf16x8*)(Kc + offF[kt][1]);
            f32x4 sacc = {0.f, 0.f, 0.f, 0.f};
            sacc = __builtin_amdgcn_mfma_f32_16x16x32_bf16(ka0, qf0, sacc, 0, 0, 0);
            sacc = __builtin_amdgcn_mfma_f32_16x16x32_bf16(ka1, qf1, sacc, 0, 0, 0);
            const f32x4 kn4 = *(const f32x4*)&knc[kt * 16 + g * 4];
            #pragma unroll
            for (int rg = 0; rg < 4; ++rg)
                sl[kt * 4 + rg] = fmaf(sacc[rg], ts2, nscal * kn4[rg]);
        }

        float p[16];
        #pragma unroll
        for (int j = 0; j < 16; ++j) {
            p[j] = __builtin_amdgcn_exp2f(sl[j]);   // native v_exp_f32
            lpart += p[j];
        }

        #pragma unroll
        for (int kt = 0; kt < 4; ++kt) {
            uint2 pk;
            pk.x = pack2bf(p[kt * 4 + 0], p[kt * 4 + 1]);
            pk.y = pack2bf(p[kt * 4 + 2], p[kt * 4 + 3]);
            *(uint2*)(Pw + offPW[kt]) = pk;
        }
        asm volatile("s_waitcnt lgkmcnt(0)" ::: "memory");
        __builtin_amdgcn_sched_barrier(0);

        const bf16x8 pa0 = *(const bf16x8*)(Pw + offPA0);
        const bf16x8 pa1 = *(const bf16x8*)(Pw + offPA1);
        #pragma unroll
        for (int dt = 0; dt < 4; ++dt) {
            const bf16x8 vb0 = *(const bf16x8*)(Vc + offF[dt][0]);
            const bf16x8 vb1 = *(const bf16x8*)(Vc + offF[dt][1]);
            acc[dt] = __builtin_amdgcn_mfma_f32_16x16x32_bf16(pa0, vb0, acc[dt], 0, 0, 0);
            acc[dt] = __builtin_amdgcn_mfma_f32_16x16x32_bf16(pa1, vb1, acc[dt], 0, 0, 0);
        }
    };

    STAGE(0, 0);
    __syncthreads();                 // drain prologue stage
    for (int T = 0; T < 32; ++T) {
        const int cur = T & 1;
        if (T < 31) STAGE(T + 1, cur ^ 1);   // overlaps with compute below
        compute_tile(cur);
        __syncthreads();             // readers done + next stage drained
    }
#undef STAGE

    lpart += __shfl_xor(lpart, 16);
    lpart += __shfl_xor(lpart, 32);

    const int b = bh >> 3, h = bh & 7;
    #pragma unroll
    for (int reg = 0; reg < 4; ++reg) {
        const float lq  = __shfl(lpart, g * 4 + reg);
        const float inv = 1.0f / lq;
        const int qg = qb * 128 + w * 16 + g * 4 + reg;
        unsigned short* dst = &VALS[((size_t)b * S_ + qg) * E_ + h * HD_];
        #pragma unroll
        for (int dt = 0; dt < 4; ++dt)
            dst[dt * 16 + c] = f2bf(acc[dt][reg] * inv);
    }
}

// ---------------------------------------------------------------------------
extern "C" void kernel_launch(void* const* d_in, const int* in_sizes, int n_in,
                              void* d_out, int out_size, void* d_ws, size_t ws_size,
                              hipStream_t stream) {
    const float* x    = (const float*)d_in[0];
    const float* Wqkv = (const float*)d_in[1];
    const float* bqkv = (const float*)d_in[2];
    const float* Wo   = (const float*)d_in[3];
    const float* bo   = (const float*)d_in[4];
    float* out = (float*)d_out;

    char* ws = (char*)d_ws;
    unsigned short* Qb    = (unsigned short*)(ws);                        // 8 MB
    unsigned short* Kb    = (unsigned short*)(ws + ((size_t) 8 << 20));   // 8 MB
    unsigned short* Vtb   = (unsigned short*)(ws + ((size_t)16 << 20));   // 8 MB
    unsigned short* VALb  = (unsigned short*)(ws + ((size_t)24 << 20));   // 8 MB
    unsigned short* xbf   = (unsigned short*)(ws + ((size_t)32 << 20));   // 8 MB
    unsigned short* Wqkvb = (unsigned short*)(ws + ((size_t)40 << 20));   // 1.5 MB
    unsigned short* Wob   = (unsigned short*)(ws + ((size_t)42 << 20));   // 0.5 MB
    float* KN2  = (float*)(ws + ((size_t)43 << 20));                      // 256 KB
    float* PART = (float*)(ws + ((size_t)43 << 20) + (256 << 10));        // 3 KB
    float* XMAX = (float*)(ws + ((size_t)43 << 20) + (260 << 10));        // 8 KB
    float* SCAL = (float*)(ws + ((size_t)43 << 20) + (272 << 10));

    // 0) x -> bf16 + per-block row-norm max; weights -> bf16 (one kernel)
    prep<<<2560, 256, 0, stream>>>(x, Wqkv, Wo, xbf, Wqkvb, Wob, XMAX);

    // 1) QKV projection (bf16 MFMA, dbuf) + sum(q^2) partials + per-key ||k||^2
    gemm_mfma<3 * E_, 0><<<dim3(12, 64), 256, 0, stream>>>(xbf, Wqkvb, bqkv, Qb, Kb, Vtb, PART, KN2);

    // 2) normalizer scalar (tiny dispatch — cheaper than any fusion tried)
    finalize_scale<<<1, 256, 0, stream>>>(PART, XMAX, SCAL);

    // 3) MFMA flash attention (R13 core, native exp2) -> VAL bf16 [B,S,E]
    attn_mfma<<<dim3(16, 32), 512, 0, stream>>>(Qb, Kb, Vtb, KN2, SCAL, VALb);

    // 4) output projection (bf16 MFMA, dbuf, fp32 out)
    gemm_mfma<E_, 1><<<dim3(4, 64), 256, 0, stream>>>(VALb, Wob, bo, out, nullptr, nullptr, nullptr, nullptr);
}